// Round 11
// baseline (109.501 us; speedup 1.0000x reference)
//
#include <hip/hip_runtime.h>
#include <cstdint>
#include <climits>

#define EPSF 1e-7f
#define NCELL 1000          // 10x10x10 cells per batch, cell size 0.1 = radius
#define RPAD 0.10002f       // radius + fuzz for f32 binning boundary safety

__device__ __forceinline__ int cell_of(float x, float y, float z) {
    int cx = min(max((int)(x * 10.0f), 0), 9);
    int cy = min(max((int)(y * 10.0f), 0), 9);
    int cz = min(max((int)(z * 10.0f), 0), 9);
    return (cx * 10 + cy) * 10 + cz;
}

// ---------------------------------------------------------------------------
// K1: one thread per face-corner (R8, works) + per-vertex cell histogram.
// ---------------------------------------------------------------------------
__global__ void k1_face_count(const float* __restrict__ hs,
                              const int* __restrict__ hf,
                              float* __restrict__ svec,
                              float* __restrict__ scnt,
                              int* __restrict__ counts,
                              int n_v, int n_f, int bs) {
    int t = blockIdx.x * blockDim.x + threadIdx.x;
    if (t < bs * n_f * 3) {
        int fid = t / 3;
        int corner = t - fid * 3;
        int b = fid / n_f;
        int f = fid - b * n_f;
        const int* fb = hf + (size_t)b * 3 * n_f;
        int i0 = fb[f];
        int i1 = fb[n_f + f];
        int i2 = fb[2 * n_f + f];
        const float* xs = hs + (size_t)b * 6 * n_v;
        const float* ys = xs + n_v;
        const float* zs = xs + 2 * n_v;
        float ax = xs[i0], ay = ys[i0], az = zs[i0];
        float bx = xs[i1], by = ys[i1], bz = zs[i1];
        float cx = xs[i2], cy = ys[i2], cz = zs[i2];
        float e1x = bx - ax, e1y = by - ay, e1z = bz - az;
        float e2x = cx - ax, e2y = cy - ay, e2z = cz - az;
        float fx = e1y * e2z - e1z * e2y;
        float fy = e1z * e2x - e1x * e2z;
        float fz = e1x * e2y - e1y * e2x;
        float nrm = sqrtf(fx * fx + fy * fy + fz * fz) + EPSF;
        fx /= nrm; fy /= nrm; fz /= nrm;
        float* sb = svec + (size_t)b * n_v * 3;
        float* cb = scnt + (size_t)b * n_v;
        int i = (corner == 0) ? i0 : ((corner == 1) ? i1 : i2);
        atomicAdd(&sb[i * 3 + 0], fx);
        atomicAdd(&sb[i * 3 + 1], fy);
        atomicAdd(&sb[i * 3 + 2], fz);
        atomicAdd(&cb[i], 1.0f);
    }
    if (t < bs * n_v) {
        int b = t / n_v;
        int v = t - b * n_v;
        const float* xs = hs + (size_t)b * 6 * n_v;
        float x = xs[v], y = xs[n_v + v], z = xs[2 * n_v + v];
        atomicAdd(&counts[b * NCELL + cell_of(x, y, z)], 1);
    }
}

// ---------------------------------------------------------------------------
// K2 (fused, 1024-thread blocks): normalize -> vert[]; per-batch scan +
// scatter (R8, works).
// ---------------------------------------------------------------------------
__global__ void k2_build(const float* __restrict__ hs,
                         const float* __restrict__ svec,
                         const float* __restrict__ scnt,
                         const int* __restrict__ counts,
                         int* __restrict__ cellstart,
                         float4* __restrict__ vert,
                         float4* __restrict__ spk,
                         int n_v, int bs, int nvb) {
    __shared__ int cursor_l[NCELL];
    if (blockIdx.x < (unsigned)nvb) {
        int t = blockIdx.x * blockDim.x + threadIdx.x;
        if (t >= bs * n_v) return;
        int b = t / n_v;
        int v = t - b * n_v;
        float cc = scnt[t] + EPSF;
        float vx = svec[t * 3 + 0] / cc;
        float vy = svec[t * 3 + 1] / cc;
        float vz = svec[t * 3 + 2] / cc;
        float nrm = sqrtf(vx * vx + vy * vy + vz * vz) + EPSF;
        const float* xs = hs + (size_t)b * 6 * n_v;
        float x = xs[v], y = xs[n_v + v], z = xs[2 * n_v + v];
        vert[2 * (size_t)t + 0] = make_float4(x, y, z, 0.0f);
        vert[2 * (size_t)t + 1] = make_float4(vx / nrm, vy / nrm, vz / nrm, 0.0f);
        return;
    }
    int batch = blockIdx.x - nvb;
    if (threadIdx.x < 64) {
        int lane = threadIdx.x;
        int local[16];
        int mysum = 0;
        #pragma unroll
        for (int k = 0; k < 16; ++k) {
            int c = lane * 16 + k;
            int v = (c < NCELL) ? counts[batch * NCELL + c] : 0;
            local[k] = v;
            mysum += v;
        }
        int s = mysum;
        #pragma unroll
        for (int off = 1; off < 64; off <<= 1) {
            int n = __shfl_up(s, off);
            if (lane >= off) s += n;
        }
        int excl = s - mysum;
        #pragma unroll
        for (int k = 0; k < 16; ++k) {
            int c = lane * 16 + k;
            if (c < NCELL) {
                cellstart[batch * (NCELL + 1) + c] = excl;
                cursor_l[c] = excl;
                excl += local[k];
            }
        }
        if (lane == 63) cellstart[batch * (NCELL + 1) + NCELL] = s;
    }
    __syncthreads();
    const float* xs = hs + (size_t)batch * 6 * n_v;
    for (int v = threadIdx.x; v < n_v; v += blockDim.x) {
        float x = xs[v], y = xs[n_v + v], z = xs[2 * n_v + v];
        int cell = cell_of(x, y, z);
        int pos = atomicAdd(&cursor_l[cell], 1);
        spk[(size_t)batch * n_v + pos] = make_float4(x, y, z, __int_as_float(v));
    }
}

// ---------------------------------------------------------------------------
// K3: R9's best structure (one query per half-wave, 8192 waves — max TLP,
// the only lever this kernel responds to) + eager round-0 loads, with
// R10's orthogonal wave-independent retirement: no LDS, no __syncthreads —
// cross-half __shfl combine, lane 0 writes one fp64 partial per wave to a
// DISTINCT address (zero device-scope sync: R2/R6 lessons).
// ---------------------------------------------------------------------------
__global__ void k3_query(const float* __restrict__ pred,
                         const float4* __restrict__ vert,
                         const float4* __restrict__ spk,
                         const int* __restrict__ cellstart,
                         double* __restrict__ partial,
                         float* __restrict__ pcnt,
                         int n_v, int n_pred, int bs) {
    const int lane = threadIdx.x & 63;
    const int wave = threadIdx.x >> 6;
    const int sub = lane & 31;          // lane within half-wave
    const int half = lane >> 5;
    const int qid = blockIdx.x * 8 + wave * 2 + half;
    const int nq = bs * n_pred;

    float per_pt = 0.0f;
    float is_pos = 0.0f;

    if (qid < nq) {
        const int b = qid / n_pred;
        const float4* vb = vert + 2 * (size_t)b * n_v;
        const float4* sp = spk + (size_t)b * n_v;
        const int* csb = cellstart + b * (NCELL + 1);
        const float px = pred[(size_t)qid * 3 + 0];
        const float py = pred[(size_t)qid * 3 + 1];
        const float pz = pred[(size_t)qid * 3 + 2];

        int xlo = max(0, (int)floorf((px - RPAD) * 10.0f));
        int xhi = min(9, (int)floorf((px + RPAD) * 10.0f));
        int ylo = max(0, (int)floorf((py - RPAD) * 10.0f));
        int yhi = min(9, (int)floorf((py + RPAD) * 10.0f));
        int zlo = max(0, (int)floorf((pz - RPAD) * 10.0f));
        int zhi = min(9, (int)floorf((pz + RPAD) * 10.0f));

        // lanes 0..8 of the half own one (cx,cy) row each: two loads give
        // all 9 z-run ranges for this half's query.
        int ip = min(sub, 8);
        int cxr = xlo + ip / 3;
        int cyr = ylo + ip % 3;
        bool validr = (cxr <= xhi) && (cyr <= yhi) && (sub < 9);
        int rowbase = (min(cxr, 9) * 10 + min(cyr, 9)) * 10;
        int rsv = csb[rowbase + zlo];
        int rev = csb[rowbase + zhi + 1];
        if (!validr) rev = rsv;         // empty run

        // broadcast all 9 run ranges
        int RS[9], RE[9];
        #pragma unroll
        for (int i = 0; i < 9; ++i) {
            RS[i] = __shfl(rsv, i, 32);
            RE[i] = __shfl(rev, i, 32);
        }

        // EAGER ROUND-0: first-32 load of every run back-to-back
        float4 c0[9];
        #pragma unroll
        for (int i = 0; i < 9; ++i) {
            int p = RS[i] + sub;
            c0[i] = sp[(p < RE[i]) ? p : 0];
        }

        int l0 = INT_MAX, l1 = INT_MAX, l2 = INT_MAX, l3 = INT_MAX;
        #pragma unroll
        for (int i = 0; i < 9; ++i) {
            if (RS[i] + sub < RE[i]) {
                float4 c4 = c0[i];
                float dx = px - c4.x;
                float dy = py - c4.y;
                float dz = pz - c4.z;
                float d2 = dx * dx + dy * dy + dz * dz;
                if (d2 < 0.01f) {           // 0.01f == f32(0.1*0.1)
                    int vid = __float_as_int(c4.w);
                    if (vid < l3) {
                        if (vid < l1) {
                            if (vid < l0) { l3 = l2; l2 = l1; l1 = l0; l0 = vid; }
                            else          { l3 = l2; l2 = l1; l1 = vid; }
                        } else {
                            if (vid < l2) { l3 = l2; l2 = vid; }
                            else          { l3 = vid; }
                        }
                    }
                }
            }
        }
        // leftovers: runs longer than 32 candidates (rare)
        #pragma unroll
        for (int i = 0; i < 9; ++i) {
            for (int p = RS[i] + 32 + sub; p < RE[i]; p += 32) {
                float4 c4 = sp[p];
                float dx = px - c4.x;
                float dy = py - c4.y;
                float dz = pz - c4.z;
                float d2 = dx * dx + dy * dy + dz * dz;
                if (d2 < 0.01f) {
                    int vid = __float_as_int(c4.w);
                    if (vid < l3) {
                        if (vid < l1) {
                            if (vid < l0) { l3 = l2; l2 = l1; l1 = l0; l0 = vid; }
                            else          { l3 = l2; l2 = l1; l1 = vid; }
                        } else {
                            if (vid < l2) { l3 = l2; l2 = vid; }
                            else          { l3 = vid; }
                        }
                    }
                }
            }
        }

        // half-wave bitonic partial merge (off=1..16 stays in the half)
        #pragma unroll
        for (int off = 1; off < 32; off <<= 1) {
            int r0 = __shfl_xor(l3, off);
            int r1 = __shfl_xor(l2, off);
            int r2 = __shfl_xor(l1, off);
            int r3 = __shfl_xor(l0, off);
            int m0 = min(l0, r0);
            int m1 = min(l1, r1);
            int m2 = min(l2, r2);
            int m3 = min(l3, r3);
            int t0 = min(m0, m2), t2 = max(m0, m2);
            int t1 = min(m1, m3), t3 = max(m1, m3);
            l0 = min(t0, t1); l1 = max(t0, t1);
            l2 = min(t2, t3); l3 = max(t2, t3);
        }

        int id0 = (l0 == INT_MAX) ? 0 : l0;      // no hits -> index 0
        int id1 = (l1 == INT_MAX) ? id0 : l1;    // unfilled -> first hit
        int id2 = (l2 == INT_MAX) ? id0 : l2;
        int id3 = (l3 == INT_MAX) ? id0 : l3;
        int ids[4] = {id0, id1, id2, id3};

        float vd[4];
        float cm = 0.0f;
        #pragma unroll
        for (int j = 0; j < 4; ++j) {
            int id = ids[j];
            float4 cj = vb[2 * id + 0];
            float4 nj = vb[2 * id + 1];
            float dx = px - cj.x;
            float dy = py - cj.y;
            float dz = pz - cj.z;
            float dot = dx * nj.x + dy * nj.y + dz * nj.z;
            float w = (dot >= -0.1f) ? 1.0f : 0.0f;
            float v = (dot - 0.001f) * w;
            bool msk = v < 0.0f;
            vd[j] = msk ? v : 0.0f;
            cm += msk ? 1.0f : 0.0f;
        }
        float s = ((vd[0] + vd[1]) + vd[2]) + vd[3];
        float a = s / (cm + EPSF);
        per_pt = a * a;
        is_pos = (per_pt > 0.0f) ? 1.0f : 0.0f;
    }

    // wave-independent retirement: cross-half combine (per_pt uniform within
    // each half after the merge), lane 0 writes one partial per wave.
    double s2 = (double)per_pt;
    float c2 = is_pos;
    double so = __shfl(s2, lane ^ 32);
    float co = __shfl(c2, lane ^ 32);
    double st = s2 + so;
    float ct = c2 + co;
    if (lane == 0) {
        int wgid = blockIdx.x * 4 + wave;       // distinct address per wave
        partial[wgid] = st;
        pcnt[wgid] = ct;
    }
}

// ---------------------------------------------------------------------------
// K4: single-block reduction of the per-wave partials -> final scalar loss.
// ---------------------------------------------------------------------------
__global__ void finalize_kernel(const double* __restrict__ partial,
                                const float* __restrict__ pcnt,
                                int n, float* __restrict__ out) {
    double s = 0.0, c = 0.0;
    for (int i = threadIdx.x; i < n; i += blockDim.x) {
        s += partial[i];
        c += (double)pcnt[i];
    }
    #pragma unroll
    for (int off = 32; off > 0; off >>= 1) {
        s += __shfl_down(s, off);
        c += __shfl_down(c, off);
    }
    __shared__ double ws_s[4];
    __shared__ double ws_c[4];
    int wave = threadIdx.x >> 6;
    int lane = threadIdx.x & 63;
    if (lane == 0) { ws_s[wave] = s; ws_c[wave] = c; }
    __syncthreads();
    if (threadIdx.x == 0) {
        double S = ws_s[0] + ws_s[1] + ws_s[2] + ws_s[3];
        double C = ws_c[0] + ws_c[1] + ws_c[2] + ws_c[3];
        out[0] = (float)(S / (C + 1e-7));
    }
}

extern "C" void kernel_launch(void* const* d_in, const int* in_sizes, int n_in,
                              void* d_out, int out_size, void* d_ws, size_t ws_size,
                              hipStream_t stream) {
    const float* pred    = (const float*)d_in[0];
    const float* h_state = (const float*)d_in[2];
    const int*   h_faces = (const int*)d_in[3];
    float* out = (float*)d_out;

    const int bs = 2;
    const int n_pred = in_sizes[0] / (bs * 3);   // 8192
    const int n_v    = in_sizes[2] / (bs * 6);   // 6890
    const int n_f    = in_sizes[3] / (bs * 3);   // 13776
    const int nq = bs * n_pred;                  // 16384
    const int nblk = (nq + 7) / 8;               // 2048 blocks, 8 queries each
    const int nwav = nblk * 4;                   // 8192 per-wave partials

    // ---- workspace layout (float-element offsets from d_ws) ----
    size_t o_svec    = 0;                                  // bs*n_v*3 (zeroed)
    size_t o_scnt    = o_svec + (size_t)bs * n_v * 3;      // bs*n_v   (zeroed)
    size_t o_counts  = o_scnt + (size_t)bs * n_v;          // bs*1000 i (zeroed)
    size_t o_zeroend = (o_counts + (size_t)bs * NCELL + 3) & ~(size_t)3;
    size_t o_cs      = o_zeroend;                          // bs*1001 i
    size_t o_partial = (o_cs + (size_t)bs * (NCELL + 1) + 1) & ~(size_t)1; // nwav d
    size_t o_pcnt    = o_partial + 2 * (size_t)nwav;       // nwav f
    size_t o_spk     = (o_pcnt + (size_t)nwav + 3) & ~(size_t)3;   // bs*n_v f4
    size_t o_vert    = o_spk + (size_t)bs * n_v * 4;               // bs*n_v*2 f4

    float* base = (float*)d_ws;
    float*  svec      = base + o_svec;
    float*  scnt      = base + o_scnt;
    int*    counts    = (int*)(base + o_counts);
    int*    cellstart = (int*)(base + o_cs);
    double* partial   = (double*)(base + o_partial);
    float*  pcnt      = base + o_pcnt;
    float4* spk       = (float4*)(base + o_spk);
    float4* vert      = (float4*)(base + o_vert);

    hipMemsetAsync(d_ws, 0, o_zeroend * sizeof(float), stream);

    int t1 = bs * n_f * 3;   // one thread per face-corner; >= bs*n_v
    k1_face_count<<<(t1 + 255) / 256, 256, 0, stream>>>(
        h_state, h_faces, svec, scnt, counts, n_v, n_f, bs);

    int nvb = (bs * n_v + 1023) / 1024;          // 14 normalize blocks @1024
    k2_build<<<nvb + bs, 1024, 0, stream>>>(
        h_state, svec, scnt, counts, cellstart, vert, spk, n_v, bs, nvb);

    k3_query<<<nblk, 256, 0, stream>>>(
        pred, vert, spk, cellstart, partial, pcnt, n_v, n_pred, bs);

    finalize_kernel<<<1, 256, 0, stream>>>(partial, pcnt, nwav, out);
}

// Round 12
// 102.337 us; speedup vs baseline: 1.0700x; 1.0700x over previous
//
#include <hip/hip_runtime.h>
#include <cstdint>
#include <climits>

#define EPSF 1e-7f
#define NCELL 1000          // 10x10x10 cells per batch, cell size 0.1 = radius
#define RPAD 0.10002f       // radius + fuzz for f32 binning boundary safety

// SESSION LESSONS (measured):
//  - R2: __threadfence in a 16k-wave kernel = cache-wide buffer_wbl2 -> +300us.
//  - R6: same-address device-scope atomics serialize cross-XCD -> +70us.
//  - R10/R11: per-wave scattered retirement costs ~7us vs one LDS-combined
//    write per block. Block-level retirement is the best measured.
//  - R4/R9: shortening the per-query load chain is neutral; R5/R8: TLP helps;
//    R10: halving waves hurts. k3 responds to wave-level parallelism only.
//  - Best measured config = this file (R9): 102.46 us, absmax 0.0.

__device__ __forceinline__ int cell_of(float x, float y, float z) {
    int cx = min(max((int)(x * 10.0f), 0), 9);
    int cy = min(max((int)(y * 10.0f), 0), 9);
    int cz = min(max((int)(z * 10.0f), 0), 9);
    return (cx * 10 + cy) * 10 + cz;
}

// ---------------------------------------------------------------------------
// K1: one thread per face-corner + per-vertex cell histogram.
// ---------------------------------------------------------------------------
__global__ void k1_face_count(const float* __restrict__ hs,
                              const int* __restrict__ hf,
                              float* __restrict__ svec,
                              float* __restrict__ scnt,
                              int* __restrict__ counts,
                              int n_v, int n_f, int bs) {
    int t = blockIdx.x * blockDim.x + threadIdx.x;
    if (t < bs * n_f * 3) {
        int fid = t / 3;
        int corner = t - fid * 3;
        int b = fid / n_f;
        int f = fid - b * n_f;
        const int* fb = hf + (size_t)b * 3 * n_f;
        int i0 = fb[f];
        int i1 = fb[n_f + f];
        int i2 = fb[2 * n_f + f];
        const float* xs = hs + (size_t)b * 6 * n_v;
        const float* ys = xs + n_v;
        const float* zs = xs + 2 * n_v;
        float ax = xs[i0], ay = ys[i0], az = zs[i0];
        float bx = xs[i1], by = ys[i1], bz = zs[i1];
        float cx = xs[i2], cy = ys[i2], cz = zs[i2];
        float e1x = bx - ax, e1y = by - ay, e1z = bz - az;
        float e2x = cx - ax, e2y = cy - ay, e2z = cz - az;
        float fx = e1y * e2z - e1z * e2y;
        float fy = e1z * e2x - e1x * e2z;
        float fz = e1x * e2y - e1y * e2x;
        float nrm = sqrtf(fx * fx + fy * fy + fz * fz) + EPSF;
        fx /= nrm; fy /= nrm; fz /= nrm;
        float* sb = svec + (size_t)b * n_v * 3;
        float* cb = scnt + (size_t)b * n_v;
        int i = (corner == 0) ? i0 : ((corner == 1) ? i1 : i2);
        atomicAdd(&sb[i * 3 + 0], fx);
        atomicAdd(&sb[i * 3 + 1], fy);
        atomicAdd(&sb[i * 3 + 2], fz);
        atomicAdd(&cb[i], 1.0f);
    }
    if (t < bs * n_v) {
        int b = t / n_v;
        int v = t - b * n_v;
        const float* xs = hs + (size_t)b * 6 * n_v;
        float x = xs[v], y = xs[n_v + v], z = xs[2 * n_v + v];
        atomicAdd(&counts[b * NCELL + cell_of(x, y, z)], 1);
    }
}

// ---------------------------------------------------------------------------
// K2 (fused, 1024-thread blocks): normalize -> vert[]; per-batch scan +
// scatter.
// ---------------------------------------------------------------------------
__global__ void k2_build(const float* __restrict__ hs,
                         const float* __restrict__ svec,
                         const float* __restrict__ scnt,
                         const int* __restrict__ counts,
                         int* __restrict__ cellstart,
                         float4* __restrict__ vert,
                         float4* __restrict__ spk,
                         int n_v, int bs, int nvb) {
    __shared__ int cursor_l[NCELL];
    if (blockIdx.x < (unsigned)nvb) {
        int t = blockIdx.x * blockDim.x + threadIdx.x;
        if (t >= bs * n_v) return;
        int b = t / n_v;
        int v = t - b * n_v;
        float cc = scnt[t] + EPSF;
        float vx = svec[t * 3 + 0] / cc;
        float vy = svec[t * 3 + 1] / cc;
        float vz = svec[t * 3 + 2] / cc;
        float nrm = sqrtf(vx * vx + vy * vy + vz * vz) + EPSF;
        const float* xs = hs + (size_t)b * 6 * n_v;
        float x = xs[v], y = xs[n_v + v], z = xs[2 * n_v + v];
        vert[2 * (size_t)t + 0] = make_float4(x, y, z, 0.0f);
        vert[2 * (size_t)t + 1] = make_float4(vx / nrm, vy / nrm, vz / nrm, 0.0f);
        return;
    }
    int batch = blockIdx.x - nvb;
    if (threadIdx.x < 64) {
        int lane = threadIdx.x;
        int local[16];
        int mysum = 0;
        #pragma unroll
        for (int k = 0; k < 16; ++k) {
            int c = lane * 16 + k;
            int v = (c < NCELL) ? counts[batch * NCELL + c] : 0;
            local[k] = v;
            mysum += v;
        }
        int s = mysum;
        #pragma unroll
        for (int off = 1; off < 64; off <<= 1) {
            int n = __shfl_up(s, off);
            if (lane >= off) s += n;
        }
        int excl = s - mysum;
        #pragma unroll
        for (int k = 0; k < 16; ++k) {
            int c = lane * 16 + k;
            if (c < NCELL) {
                cellstart[batch * (NCELL + 1) + c] = excl;
                cursor_l[c] = excl;
                excl += local[k];
            }
        }
        if (lane == 63) cellstart[batch * (NCELL + 1) + NCELL] = s;
    }
    __syncthreads();
    const float* xs = hs + (size_t)batch * 6 * n_v;
    for (int v = threadIdx.x; v < n_v; v += blockDim.x) {
        float x = xs[v], y = xs[n_v + v], z = xs[2 * n_v + v];
        int cell = cell_of(x, y, z);
        int pos = atomicAdd(&cursor_l[cell], 1);
        spk[(size_t)batch * n_v + pos] = make_float4(x, y, z, __int_as_float(v));
    }
}

// ---------------------------------------------------------------------------
// K3: half-wave queries (one query per 32 lanes, 8192 waves) + eager
// round-0 candidate loads + BLOCK-LEVEL LDS retirement (measured best).
// ---------------------------------------------------------------------------
__global__ void k3_query(const float* __restrict__ pred,
                         const float4* __restrict__ vert,
                         const float4* __restrict__ spk,
                         const int* __restrict__ cellstart,
                         double* __restrict__ partial,
                         float* __restrict__ pcnt,
                         int n_v, int n_pred, int bs) {
    const int lane = threadIdx.x & 63;
    const int wave = threadIdx.x >> 6;
    const int sub = lane & 31;          // lane within half-wave
    const int half = lane >> 5;
    const int qid = blockIdx.x * 8 + wave * 2 + half;
    const int nq = bs * n_pred;

    float per_pt = 0.0f;
    float is_pos = 0.0f;

    if (qid < nq) {
        const int b = qid / n_pred;
        const float4* vb = vert + 2 * (size_t)b * n_v;
        const float4* sp = spk + (size_t)b * n_v;
        const int* csb = cellstart + b * (NCELL + 1);
        const float px = pred[(size_t)qid * 3 + 0];
        const float py = pred[(size_t)qid * 3 + 1];
        const float pz = pred[(size_t)qid * 3 + 2];

        int xlo = max(0, (int)floorf((px - RPAD) * 10.0f));
        int xhi = min(9, (int)floorf((px + RPAD) * 10.0f));
        int ylo = max(0, (int)floorf((py - RPAD) * 10.0f));
        int yhi = min(9, (int)floorf((py + RPAD) * 10.0f));
        int zlo = max(0, (int)floorf((pz - RPAD) * 10.0f));
        int zhi = min(9, (int)floorf((pz + RPAD) * 10.0f));

        int ip = min(sub, 8);
        int cxr = xlo + ip / 3;
        int cyr = ylo + ip % 3;
        bool validr = (cxr <= xhi) && (cyr <= yhi) && (sub < 9);
        int rowbase = (min(cxr, 9) * 10 + min(cyr, 9)) * 10;
        int rsv = csb[rowbase + zlo];
        int rev = csb[rowbase + zhi + 1];
        if (!validr) rev = rsv;         // empty run

        int RS[9], RE[9];
        #pragma unroll
        for (int i = 0; i < 9; ++i) {
            RS[i] = __shfl(rsv, i, 32);
            RE[i] = __shfl(rev, i, 32);
        }

        float4 c0[9];
        #pragma unroll
        for (int i = 0; i < 9; ++i) {
            int p = RS[i] + sub;
            c0[i] = sp[(p < RE[i]) ? p : 0];
        }

        int l0 = INT_MAX, l1 = INT_MAX, l2 = INT_MAX, l3 = INT_MAX;
        #pragma unroll
        for (int i = 0; i < 9; ++i) {
            if (RS[i] + sub < RE[i]) {
                float4 c4 = c0[i];
                float dx = px - c4.x;
                float dy = py - c4.y;
                float dz = pz - c4.z;
                float d2 = dx * dx + dy * dy + dz * dz;
                if (d2 < 0.01f) {           // 0.01f == f32(0.1*0.1)
                    int vid = __float_as_int(c4.w);
                    if (vid < l3) {
                        if (vid < l1) {
                            if (vid < l0) { l3 = l2; l2 = l1; l1 = l0; l0 = vid; }
                            else          { l3 = l2; l2 = l1; l1 = vid; }
                        } else {
                            if (vid < l2) { l3 = l2; l2 = vid; }
                            else          { l3 = vid; }
                        }
                    }
                }
            }
        }
        #pragma unroll
        for (int i = 0; i < 9; ++i) {
            for (int p = RS[i] + 32 + sub; p < RE[i]; p += 32) {
                float4 c4 = sp[p];
                float dx = px - c4.x;
                float dy = py - c4.y;
                float dz = pz - c4.z;
                float d2 = dx * dx + dy * dy + dz * dz;
                if (d2 < 0.01f) {
                    int vid = __float_as_int(c4.w);
                    if (vid < l3) {
                        if (vid < l1) {
                            if (vid < l0) { l3 = l2; l2 = l1; l1 = l0; l0 = vid; }
                            else          { l3 = l2; l2 = l1; l1 = vid; }
                        } else {
                            if (vid < l2) { l3 = l2; l2 = vid; }
                            else          { l3 = vid; }
                        }
                    }
                }
            }
        }

        #pragma unroll
        for (int off = 1; off < 32; off <<= 1) {
            int r0 = __shfl_xor(l3, off);
            int r1 = __shfl_xor(l2, off);
            int r2 = __shfl_xor(l1, off);
            int r3 = __shfl_xor(l0, off);
            int m0 = min(l0, r0);
            int m1 = min(l1, r1);
            int m2 = min(l2, r2);
            int m3 = min(l3, r3);
            int t0 = min(m0, m2), t2 = max(m0, m2);
            int t1 = min(m1, m3), t3 = max(m1, m3);
            l0 = min(t0, t1); l1 = max(t0, t1);
            l2 = min(t2, t3); l3 = max(t2, t3);
        }

        int id0 = (l0 == INT_MAX) ? 0 : l0;      // no hits -> index 0
        int id1 = (l1 == INT_MAX) ? id0 : l1;    // unfilled -> first hit
        int id2 = (l2 == INT_MAX) ? id0 : l2;
        int id3 = (l3 == INT_MAX) ? id0 : l3;
        int ids[4] = {id0, id1, id2, id3};

        float vd[4];
        float cm = 0.0f;
        #pragma unroll
        for (int j = 0; j < 4; ++j) {
            int id = ids[j];
            float4 cj = vb[2 * id + 0];
            float4 nj = vb[2 * id + 1];
            float dx = px - cj.x;
            float dy = py - cj.y;
            float dz = pz - cj.z;
            float dot = dx * nj.x + dy * nj.y + dz * nj.z;
            float w = (dot >= -0.1f) ? 1.0f : 0.0f;
            float v = (dot - 0.001f) * w;
            bool msk = v < 0.0f;
            vd[j] = msk ? v : 0.0f;
            cm += msk ? 1.0f : 0.0f;
        }
        float s = ((vd[0] + vd[1]) + vd[2]) + vd[3];
        float a = s / (cm + EPSF);
        per_pt = a * a;
        is_pos = (per_pt > 0.0f) ? 1.0f : 0.0f;
    }

    __shared__ float ls[8];
    __shared__ float lc[8];
    if (sub == 0) {
        int slot = wave * 2 + half;
        ls[slot] = per_pt;
        lc[slot] = is_pos;
    }
    __syncthreads();
    if (threadIdx.x == 0) {
        double ssum = 0.0;
        float csum = 0.0f;
        #pragma unroll
        for (int k = 0; k < 8; ++k) {
            ssum += (double)ls[k];
            csum += lc[k];
        }
        partial[blockIdx.x] = ssum;     // distinct address per block
        pcnt[blockIdx.x] = csum;
    }
}

// ---------------------------------------------------------------------------
// K4: single-block reduction of the block partials -> final scalar loss.
// ---------------------------------------------------------------------------
__global__ void finalize_kernel(const double* __restrict__ partial,
                                const float* __restrict__ pcnt,
                                int n, float* __restrict__ out) {
    double s = 0.0, c = 0.0;
    for (int i = threadIdx.x; i < n; i += blockDim.x) {
        s += partial[i];
        c += (double)pcnt[i];
    }
    #pragma unroll
    for (int off = 32; off > 0; off >>= 1) {
        s += __shfl_down(s, off);
        c += __shfl_down(c, off);
    }
    __shared__ double ws_s[4];
    __shared__ double ws_c[4];
    int wave = threadIdx.x >> 6;
    int lane = threadIdx.x & 63;
    if (lane == 0) { ws_s[wave] = s; ws_c[wave] = c; }
    __syncthreads();
    if (threadIdx.x == 0) {
        double S = ws_s[0] + ws_s[1] + ws_s[2] + ws_s[3];
        double C = ws_c[0] + ws_c[1] + ws_c[2] + ws_c[3];
        out[0] = (float)(S / (C + 1e-7));
    }
}

extern "C" void kernel_launch(void* const* d_in, const int* in_sizes, int n_in,
                              void* d_out, int out_size, void* d_ws, size_t ws_size,
                              hipStream_t stream) {
    const float* pred    = (const float*)d_in[0];
    const float* h_state = (const float*)d_in[2];
    const int*   h_faces = (const int*)d_in[3];
    float* out = (float*)d_out;

    const int bs = 2;
    const int n_pred = in_sizes[0] / (bs * 3);   // 8192
    const int n_v    = in_sizes[2] / (bs * 6);   // 6890
    const int n_f    = in_sizes[3] / (bs * 3);   // 13776
    const int nq = bs * n_pred;                  // 16384
    const int nblk = (nq + 7) / 8;               // 2048 blocks, 8 queries each

    // ---- workspace layout (float-element offsets from d_ws) ----
    size_t o_svec    = 0;                                  // bs*n_v*3 (zeroed)
    size_t o_scnt    = o_svec + (size_t)bs * n_v * 3;      // bs*n_v   (zeroed)
    size_t o_counts  = o_scnt + (size_t)bs * n_v;          // bs*1000 i (zeroed)
    size_t o_zeroend = (o_counts + (size_t)bs * NCELL + 3) & ~(size_t)3;
    size_t o_cs      = o_zeroend;                          // bs*1001 i
    size_t o_partial = (o_cs + (size_t)bs * (NCELL + 1) + 1) & ~(size_t)1; // nblk d
    size_t o_pcnt    = o_partial + 2 * (size_t)nblk;       // nblk f
    size_t o_spk     = (o_pcnt + (size_t)nblk + 3) & ~(size_t)3;   // bs*n_v f4
    size_t o_vert    = o_spk + (size_t)bs * n_v * 4;               // bs*n_v*2 f4

    float* base = (float*)d_ws;
    float*  svec      = base + o_svec;
    float*  scnt      = base + o_scnt;
    int*    counts    = (int*)(base + o_counts);
    int*    cellstart = (int*)(base + o_cs);
    double* partial   = (double*)(base + o_partial);
    float*  pcnt      = base + o_pcnt;
    float4* spk       = (float4*)(base + o_spk);
    float4* vert      = (float4*)(base + o_vert);

    hipMemsetAsync(d_ws, 0, o_zeroend * sizeof(float), stream);

    int t1 = bs * n_f * 3;   // one thread per face-corner; >= bs*n_v
    k1_face_count<<<(t1 + 255) / 256, 256, 0, stream>>>(
        h_state, h_faces, svec, scnt, counts, n_v, n_f, bs);

    int nvb = (bs * n_v + 1023) / 1024;          // 14 normalize blocks @1024
    k2_build<<<nvb + bs, 1024, 0, stream>>>(
        h_state, svec, scnt, counts, cellstart, vert, spk, n_v, bs, nvb);

    k3_query<<<nblk, 256, 0, stream>>>(
        pred, vert, spk, cellstart, partial, pcnt, n_v, n_pred, bs);

    finalize_kernel<<<1, 256, 0, stream>>>(partial, pcnt, nblk, out);
}